// Round 6
// baseline (503.241 us; speedup 1.0000x reference)
//
#include <hip/hip_runtime.h>
#include <hip/hip_bf16.h>

#define B_ 4
#define N_ 2048
#define D_ 768
#define H_ 6
#define Do_ 128
#define M_ (B_*N_)      // 8192
#define C2_ (2*D_)      // 1536

typedef __attribute__((ext_vector_type(8))) short bf16x8;
typedef __attribute__((ext_vector_type(4))) float f32x4;
typedef __attribute__((ext_vector_type(4))) int int4v;
typedef __attribute__((ext_vector_type(4))) float float4v;
typedef __attribute__((ext_vector_type(4))) unsigned short ushort4v;

__device__ __forceinline__ float b2f(short s){
    unsigned u = ((unsigned)(unsigned short)s) << 16;
    return __builtin_bit_cast(float, u);
}
__device__ __forceinline__ short f2b(float f){
    unsigned u = __builtin_bit_cast(unsigned, f);
    unsigned r = (u + 0x7fffu + ((u >> 16) & 1u)) >> 16;
    return (short)r;
}
__device__ __forceinline__ float fast_tanh(float x){
    float a = fabsf(x);
    float e = __expf(-2.0f * a);
    float t = (1.0f - e) / (1.0f + e);
    return copysignf(t, x);
}

// -------- Kernel A: pack B^T matrix [1536][768] (f32 -> bf16) --------
// rows 0..767   : c = hd*128+o -> W[hd][k][o]
// rows 768..1535: c = 768+d    -> H_w[d][k]
__global__ __launch_bounds__(256) void k_prep(const float* __restrict__ W,
                                              const float* __restrict__ Hw,
                                              short* __restrict__ bmat){
    int c = blockIdx.x, t = threadIdx.x;
    if (c < D_){
        int hd = c >> 7, o = c & 127;
        const float* wp = W + hd*D_*Do_ + o;
        for (int k = t; k < D_; k += 256) bmat[c*D_ + k] = f2b(wp[k*Do_]);
    } else {
        int d = c - D_;
        const float* hp = Hw + d*D_;
        for (int k = t; k < D_; k += 256) bmat[c*D_ + k] = f2b(hp[k]);
    }
}

// -------- Kernel B: C[8192,1536] = A[8192,768] @ BmatT^T --------
// A = f32 feat_in, converted to bf16 during LDS staging.
// h part (c<768) stored TRANSPOSED: ht[(bh*128+o)*2048 + n], bf16
// gate part (c>=768): gate logits written as f32 into d_out: outg[m*768 + d]
__global__ __launch_bounds__(256) void k_gemm(const float* __restrict__ A,
                                              const short* __restrict__ Bm,
                                              short* __restrict__ ht,
                                              float* outg){
    __shared__ short As[64][72];   // +8 pad keeps 16B align (144B rows)
    __shared__ short Bs[64][72];
    int tid = threadIdx.x;
    int mBase = blockIdx.y * 64, cBase = blockIdx.x * 64;
    int wave = tid >> 6, lane = tid & 63, q = lane >> 4, nL = lane & 15;
    int wRow = (wave >> 1) * 32, wCol = (wave & 1) * 32;
    f32x4 acc[2][2] = {};
    for (int kk = 0; kk < D_; kk += 64){
        __syncthreads();
        #pragma unroll
        for (int i = 0; i < 4; i++){
            int id = tid + i*256;                  // [0,1024)
            int row = id >> 4, c4 = (id & 15) * 4; // 16 float4-chunks per 64-wide row
            float4v av = *(const float4v*)&A[(mBase+row)*D_ + kk + c4];
            ushort4v sv;
            #pragma unroll
            for (int t = 0; t < 4; t++) sv[t] = (unsigned short)f2b(av[t]);
            *(ushort4v*)&As[row][c4] = sv;
        }
        #pragma unroll
        for (int i = 0; i < 2; i++){
            int id = tid + i*256;                  // [0,512)
            int row = id >> 3, cs = (id & 7) * 8;
            *(int4v*)&Bs[row][cs] = *(const int4v*)&Bm[(cBase+row)*D_ + kk + cs];
        }
        __syncthreads();
        #pragma unroll
        for (int k2 = 0; k2 < 64; k2 += 32){
            bf16x8 aF[2], bF[2];
            #pragma unroll
            for (int rt = 0; rt < 2; rt++) aF[rt] = *(const bf16x8*)&As[wRow + rt*16 + nL][k2 + q*8];
            #pragma unroll
            for (int ct = 0; ct < 2; ct++) bF[ct] = *(const bf16x8*)&Bs[wCol + ct*16 + nL][k2 + q*8];
            #pragma unroll
            for (int rt = 0; rt < 2; rt++)
                #pragma unroll
                for (int ct = 0; ct < 2; ct++)
                    acc[rt][ct] = __builtin_amdgcn_mfma_f32_16x16x32_bf16(aF[rt], bF[ct], acc[rt][ct], 0, 0, 0);
        }
    }
    #pragma unroll
    for (int rt = 0; rt < 2; rt++){
        #pragma unroll
        for (int ct = 0; ct < 2; ct++){
            int c  = cBase + wCol + ct*16 + nL;
            int m0 = mBase + wRow + rt*16 + q*4;   // rows m0..m0+3 (C row = q*4+r)
            if (c < D_){
                int hd = c >> 7, o = c & 127;
                int b = m0 >> 11, n0 = m0 & 2047;
                ushort4v v;
                #pragma unroll
                for (int r = 0; r < 4; r++) v[r] = (unsigned short)f2b(acc[rt][ct][r]);
                *(ushort4v*)&ht[((b*H_ + hd)*Do_ + o)*N_ + n0] = v;
            } else {
                int d = c - D_;
                #pragma unroll
                for (int r = 0; r < 4; r++) outg[(size_t)(m0 + r)*D_ + d] = acc[rt][ct][r];
            }
        }
    }
}

// -------- Kernel C: attn_src/dst = tanh(h) . w --------
__global__ __launch_bounds__(256) void k_stats(const short* __restrict__ ht,
                                               const float* __restrict__ wsrc,
                                               const float* __restrict__ wdst,
                                               float* __restrict__ src,
                                               float* __restrict__ dst){
    int g = blockIdx.x * 256 + threadIdx.x;     // g = bh*2048 + n
    int bh = g >> 11, n = g & 2047;
    int hd = bh % H_;
    const short* hp = ht + bh*Do_*N_ + n;
    const float* ws = wsrc + hd*Do_;
    const float* wd = wdst + hd*Do_;
    float as = 0.f, ad = 0.f;
    for (int o = 0; o < Do_; o++){
        float t = fast_tanh(b2f(hp[o*N_]));
        as += t * ws[o];
        ad += t * wd[o];
    }
    src[g] = as; dst[g] = ad;
}

// -------- Kernel D: per-row softmax max & sum --------
__global__ __launch_bounds__(256) void k_rowstats(const int* __restrict__ adj,
                                                  const float* __restrict__ src,
                                                  const float* __restrict__ dst,
                                                  float* __restrict__ mrow,
                                                  float* __restrict__ lrow){
    int i = blockIdx.x, b = blockIdx.y, tid = threadIdx.x;
    float sv[H_];
    #pragma unroll
    for (int h = 0; h < H_; h++) sv[h] = src[(b*H_ + h)*N_ + i];
    float mm[H_], ll[H_];
    #pragma unroll
    for (int h = 0; h < H_; h++){ mm[h] = -1e30f; ll[h] = 0.f; }
    const int* ar = adj + (size_t)(b*N_ + i)*N_;
    const float* dp = dst + b*H_*N_;
    for (int j = tid; j < N_; j += 256){
        int a = ar[j];
        #pragma unroll
        for (int h = 0; h < H_; h++){
            float v = sv[h] + dp[h*N_ + j];
            float s = v >= 0.f ? v : 0.2f*v;
            s = a ? s : -999.0f;
            float M = fmaxf(mm[h], s);
            ll[h] = ll[h]*__expf(mm[h] - M) + __expf(s - M);
            mm[h] = M;
        }
    }
    #pragma unroll
    for (int h = 0; h < H_; h++){
        for (int off = 32; off; off >>= 1){
            float om = __shfl_xor(mm[h], off);
            float ol = __shfl_xor(ll[h], off);
            float M = fmaxf(mm[h], om);
            ll[h] = ll[h]*__expf(mm[h] - M) + ol*__expf(om - M);
            mm[h] = M;
        }
    }
    __shared__ float rm[4][H_], rl[4][H_];
    int wave = tid >> 6, lane = tid & 63;
    if (lane == 0){
        #pragma unroll
        for (int h = 0; h < H_; h++){ rm[wave][h] = mm[h]; rl[wave][h] = ll[h]; }
    }
    __syncthreads();
    if (tid < H_){
        float M = rm[0][tid], L = rl[0][tid];
        #pragma unroll
        for (int w = 1; w < 4; w++){
            float M2 = fmaxf(M, rm[w][tid]);
            L = L*__expf(M - M2) + rl[w][tid]*__expf(rm[w][tid] - M2);
            M = M2;
        }
        mrow[(b*H_ + tid)*N_ + i] = M;
        lrow[(b*H_ + tid)*N_ + i] = L;
    }
}

// -------- Kernel E: O = P @ h, fused epilogue (f32 output) --------
// block = 4 waves; wave handles 16 rows x 128 cols. P-fragment computed
// in-register in MFMA A-layout (m=lane&15, k=quad*8+t). ht transposed ->
// B-fragment is one contiguous 16B load. Gate logit (f32) is read from outg
// and the SAME element is then overwritten with the final f32 result.
__global__ __launch_bounds__(256) void k_pv(const int* __restrict__ adj,
                                            const float* __restrict__ src,
                                            const float* __restrict__ dstA,
                                            const float* __restrict__ mrow,
                                            const float* __restrict__ lrow,
                                            const short* __restrict__ ht,
                                            const float* __restrict__ feat_in,
                                            const float* __restrict__ bias,
                                            const float* __restrict__ Hb,
                                            float* outg){
    int itile = blockIdx.x, hd = blockIdx.y, b = blockIdx.z;
    int tid = threadIdx.x, wave = tid >> 6, lane = tid & 63, q = lane >> 4, nL = lane & 15;
    int row = itile*64 + wave*16 + nL;          // A-fragment row for this lane
    int bh = b*H_ + hd;
    float srcv = src[bh*N_ + row];
    float mr   = mrow[bh*N_ + row];
    const int*   ar = adj  + (size_t)(b*N_ + row)*N_;
    const float* dp = dstA + bh*N_;
    const short* hp = ht   + bh*Do_*N_;
    f32x4 acc[8] = {};
    for (int j0 = 0; j0 < N_; j0 += 32){
        int kb = j0 + q*8;
        int4v   a0 = *(const int4v*)&ar[kb];
        int4v   a1 = *(const int4v*)&ar[kb + 4];
        float4v d0 = *(const float4v*)&dp[kb];
        float4v d1 = *(const float4v*)&dp[kb + 4];
        bf16x8 pf;
        #pragma unroll
        for (int t = 0; t < 8; t++){
            int   a  = t < 4 ? a0[t] : a1[t-4];
            float dv = t < 4 ? d0[t] : d1[t-4];
            float v = srcv + dv;
            float s = v >= 0.f ? v : 0.2f*v;
            s = a ? s : -999.0f;
            pf[t] = f2b(__expf(s - mr));
        }
        #pragma unroll
        for (int ct = 0; ct < 8; ct++){
            bf16x8 bF = *(const bf16x8*)&hp[(ct*16 + nL)*N_ + kb];
            acc[ct] = __builtin_amdgcn_mfma_f32_16x16x32_bf16(pf, bF, acc[ct], 0, 0, 0);
        }
    }
    #pragma unroll
    for (int r = 0; r < 4; r++){
        int i = itile*64 + wave*16 + q*4 + r;   // C row = q*4+r
        float invl = 1.0f / lrow[bh*N_ + i];
        size_t base = (size_t)(b*N_ + i)*D_ + hd*Do_;
        #pragma unroll
        for (int ct = 0; ct < 8; ct++){
            int o = ct*16 + nL;                  // C col = lane&15
            float v = acc[ct][r]*invl + bias[o];
            float e = v > 0.f ? v : __expf(v) - 1.0f;
            float gl = outg[base + o] + Hb[hd*Do_ + o];
            float g = 1.0f / (1.0f + __expf(-gl));
            float fi = feat_in[base + o];
            outg[base + o] = g*e + (1.0f - g)*fi;
        }
    }
}

extern "C" void kernel_launch(void* const* d_in, const int* in_sizes, int n_in,
                              void* d_out, int out_size, void* d_ws, size_t ws_size,
                              hipStream_t stream){
    const float* feat = (const float*)d_in[0];
    const int*   adj  = (const int*)  d_in[1];
    const float* W    = (const float*)d_in[2];
    const float* bias = (const float*)d_in[3];
    const float* wsrc = (const float*)d_in[4];
    const float* wdst = (const float*)d_in[5];
    const float* Hw   = (const float*)d_in[6];
    const float* Hb   = (const float*)d_in[7];
    float* out = (float*)d_out;                 // f32 output per reference dtype
    char* ws = (char*)d_ws;
    // Workspace (15,728,640 bytes total, no overlap):
    //   bmat [0, 2,359,296)
    //   ht   [2,359,296, 14,942,208)
    //   src  [14,942,208, 15,138,816)
    //   dst  [15,138,816, 15,335,424)
    //   mrow [15,335,424, 15,532,032)
    //   lrow [15,532,032, 15,728,640)
    short* bmat = (short*)(ws);
    short* ht   = (short*)(ws + 2359296);
    float* src  = (float*)(ws + 14942208);
    float* dst  = (float*)(ws + 15138816);
    float* mrow = (float*)(ws + 15335424);
    float* lrow = (float*)(ws + 15532032);

    hipLaunchKernelGGL(k_prep,     dim3(C2_),     dim3(256), 0, stream, W, Hw, bmat);
    hipLaunchKernelGGL(k_gemm,     dim3(24, 128), dim3(256), 0, stream, feat, bmat, ht, out);
    hipLaunchKernelGGL(k_stats,    dim3(192),     dim3(256), 0, stream, ht, wsrc, wdst, src, dst);
    hipLaunchKernelGGL(k_rowstats, dim3(2048, 4), dim3(256), 0, stream, adj, src, dst, mrow, lrow);
    hipLaunchKernelGGL(k_pv,       dim3(32, 6, 4),dim3(256), 0, stream, adj, src, dst, mrow, lrow,
                       ht, feat, bias, Hb, out);
}

// Round 7
// 467.998 us; speedup vs baseline: 1.0753x; 1.0753x over previous
//
#include <hip/hip_runtime.h>
#include <hip/hip_bf16.h>

#define B_ 4
#define N_ 2048
#define D_ 768
#define H_ 6
#define Do_ 128
#define M_ (B_*N_)      // 8192
#define C2_ (2*D_)      // 1536

typedef __attribute__((ext_vector_type(8))) short bf16x8;
typedef __attribute__((ext_vector_type(4))) float f32x4;
typedef __attribute__((ext_vector_type(4))) int int4v;
typedef __attribute__((ext_vector_type(4))) float float4v;
typedef __attribute__((ext_vector_type(4))) unsigned short ushort4v;

__device__ __forceinline__ float b2f(short s){
    unsigned u = ((unsigned)(unsigned short)s) << 16;
    return __builtin_bit_cast(float, u);
}
__device__ __forceinline__ short f2b(float f){
    unsigned u = __builtin_bit_cast(unsigned, f);
    unsigned r = (u + 0x7fffu + ((u >> 16) & 1u)) >> 16;
    return (short)r;
}
__device__ __forceinline__ float fast_tanh(float x){
    float a = fabsf(x);
    float e = __expf(-2.0f * a);
    float t = (1.0f - e) / (1.0f + e);
    return copysignf(t, x);
}

// -------- Kernel A: pack B^T matrix [1536][768] (f32 -> bf16) --------
__global__ __launch_bounds__(256) void k_prep(const float* __restrict__ W,
                                              const float* __restrict__ Hw,
                                              short* __restrict__ bmat){
    int c = blockIdx.x, t = threadIdx.x;
    if (c < D_){
        int hd = c >> 7, o = c & 127;
        const float* wp = W + hd*D_*Do_ + o;
        for (int k = t; k < D_; k += 256) bmat[c*D_ + k] = f2b(wp[k*Do_]);
    } else {
        int d = c - D_;
        const float* hp = Hw + d*D_;
        for (int k = t; k < D_; k += 256) bmat[c*D_ + k] = f2b(hp[k]);
    }
}

// -------- Kernel A2: bit-pack adj (int 0/1 -> 1 bit), 67MB -> 2MB --------
__global__ __launch_bounds__(256) void k_pack(const int* __restrict__ adj,
                                              unsigned char* __restrict__ pk){
    int t = blockIdx.x*256 + threadIdx.x;   // one output byte per thread
    const int* ap = adj + (size_t)t*8;
    int4v a0 = *(const int4v*)ap;
    int4v a1 = *(const int4v*)(ap + 4);
    unsigned by = 0;
    #pragma unroll
    for (int i = 0; i < 4; i++){
        by |= (a0[i] ? 1u : 0u) << i;
        by |= (a1[i] ? 1u : 0u) << (i + 4);
    }
    pk[t] = (unsigned char)by;
}

// -------- Kernel B: C[8192,1536] = A[8192,768] @ BmatT^T --------
__global__ __launch_bounds__(256) void k_gemm(const float* __restrict__ A,
                                              const short* __restrict__ Bm,
                                              short* __restrict__ ht,
                                              float* outg){
    __shared__ short As[64][72];
    __shared__ short Bs[64][72];
    int tid = threadIdx.x;
    int mBase = blockIdx.y * 64, cBase = blockIdx.x * 64;
    int wave = tid >> 6, lane = tid & 63, q = lane >> 4, nL = lane & 15;
    int wRow = (wave >> 1) * 32, wCol = (wave & 1) * 32;
    f32x4 acc[2][2] = {};
    for (int kk = 0; kk < D_; kk += 64){
        __syncthreads();
        #pragma unroll
        for (int i = 0; i < 4; i++){
            int id = tid + i*256;
            int row = id >> 4, c4 = (id & 15) * 4;
            float4v av = *(const float4v*)&A[(mBase+row)*D_ + kk + c4];
            ushort4v sv;
            #pragma unroll
            for (int t = 0; t < 4; t++) sv[t] = (unsigned short)f2b(av[t]);
            *(ushort4v*)&As[row][c4] = sv;
        }
        #pragma unroll
        for (int i = 0; i < 2; i++){
            int id = tid + i*256;
            int row = id >> 3, cs = (id & 7) * 8;
            *(int4v*)&Bs[row][cs] = *(const int4v*)&Bm[(cBase+row)*D_ + kk + cs];
        }
        __syncthreads();
        #pragma unroll
        for (int k2 = 0; k2 < 64; k2 += 32){
            bf16x8 aF[2], bF[2];
            #pragma unroll
            for (int rt = 0; rt < 2; rt++) aF[rt] = *(const bf16x8*)&As[wRow + rt*16 + nL][k2 + q*8];
            #pragma unroll
            for (int ct = 0; ct < 2; ct++) bF[ct] = *(const bf16x8*)&Bs[wCol + ct*16 + nL][k2 + q*8];
            #pragma unroll
            for (int rt = 0; rt < 2; rt++)
                #pragma unroll
                for (int ct = 0; ct < 2; ct++)
                    acc[rt][ct] = __builtin_amdgcn_mfma_f32_16x16x32_bf16(aF[rt], bF[ct], acc[rt][ct], 0, 0, 0);
        }
    }
    #pragma unroll
    for (int rt = 0; rt < 2; rt++){
        #pragma unroll
        for (int ct = 0; ct < 2; ct++){
            int c  = cBase + wCol + ct*16 + nL;
            int m0 = mBase + wRow + rt*16 + q*4;
            if (c < D_){
                int hd = c >> 7, o = c & 127;
                int b = m0 >> 11, n0 = m0 & 2047;
                ushort4v v;
                #pragma unroll
                for (int r = 0; r < 4; r++) v[r] = (unsigned short)f2b(acc[rt][ct][r]);
                *(ushort4v*)&ht[((b*H_ + hd)*Do_ + o)*N_ + n0] = v;
            } else {
                int d = c - D_;
                #pragma unroll
                for (int r = 0; r < 4; r++) outg[(size_t)(m0 + r)*D_ + d] = acc[rt][ct][r];
            }
        }
    }
}

// -------- Kernel C: attn_src/dst = tanh(h) . w --------
__global__ __launch_bounds__(256) void k_stats(const short* __restrict__ ht,
                                               const float* __restrict__ wsrc,
                                               const float* __restrict__ wdst,
                                               float* __restrict__ src,
                                               float* __restrict__ dst){
    int g = blockIdx.x * 256 + threadIdx.x;
    int bh = g >> 11, n = g & 2047;
    int hd = bh % H_;
    const short* hp = ht + bh*Do_*N_ + n;
    const float* ws = wsrc + hd*Do_;
    const float* wd = wdst + hd*Do_;
    float as = 0.f, ad = 0.f;
    for (int o = 0; o < Do_; o++){
        float t = fast_tanh(b2f(hp[o*N_]));
        as += t * ws[o];
        ad += t * wd[o];
    }
    src[g] = as; dst[g] = ad;
}

// -------- Kernel D: per-row softmax max & sum --------
__global__ __launch_bounds__(256) void k_rowstats(const int* __restrict__ adj,
                                                  const float* __restrict__ src,
                                                  const float* __restrict__ dst,
                                                  float* __restrict__ mrow,
                                                  float* __restrict__ lrow){
    int i = blockIdx.x, b = blockIdx.y, tid = threadIdx.x;
    float sv[H_];
    #pragma unroll
    for (int h = 0; h < H_; h++) sv[h] = src[(b*H_ + h)*N_ + i];
    float mm[H_], ll[H_];
    #pragma unroll
    for (int h = 0; h < H_; h++){ mm[h] = -1e30f; ll[h] = 0.f; }
    const int* ar = adj + (size_t)(b*N_ + i)*N_;
    const float* dp = dst + b*H_*N_;
    for (int j = tid; j < N_; j += 256){
        int a = ar[j];
        #pragma unroll
        for (int h = 0; h < H_; h++){
            float v = sv[h] + dp[h*N_ + j];
            float s = v >= 0.f ? v : 0.2f*v;
            s = a ? s : -999.0f;
            float M = fmaxf(mm[h], s);
            ll[h] = ll[h]*__expf(mm[h] - M) + __expf(s - M);
            mm[h] = M;
        }
    }
    #pragma unroll
    for (int h = 0; h < H_; h++){
        for (int off = 32; off; off >>= 1){
            float om = __shfl_xor(mm[h], off);
            float ol = __shfl_xor(ll[h], off);
            float M = fmaxf(mm[h], om);
            ll[h] = ll[h]*__expf(mm[h] - M) + ol*__expf(om - M);
            mm[h] = M;
        }
    }
    __shared__ float rm[4][H_], rl[4][H_];
    int wave = tid >> 6, lane = tid & 63;
    if (lane == 0){
        #pragma unroll
        for (int h = 0; h < H_; h++){ rm[wave][h] = mm[h]; rl[wave][h] = ll[h]; }
    }
    __syncthreads();
    if (tid < H_){
        float M = rm[0][tid], L = rl[0][tid];
        #pragma unroll
        for (int w = 1; w < 4; w++){
            float M2 = fmaxf(M, rm[w][tid]);
            L = L*__expf(M - M2) + rl[w][tid]*__expf(rm[w][tid] - M2);
            M = M2;
        }
        mrow[(b*H_ + tid)*N_ + i] = M;
        lrow[(b*H_ + tid)*N_ + i] = L;
    }
}

// -------- Kernel E: O = P @ h, K-split 2x, LDS-staged adj-bits + dst --------
// Block = 256 thr = 4 waves: wave (rg, kh); rg = row-group (16 rows), kh = K-half.
// Each wave: 16 rows x 128 cols over j in [kh*1024, kh*1024+1024).
// Partials combined through LDS; kh==0 waves run the fused epilogue.
struct StageS {
    float dst[2048];            // 8 KB
    unsigned pkw[32*65];        // packed adj bits, 65-u32 row stride (bank-conflict-free)
};
union LdsU {
    StageS s;
    float red[2][64][33];       // +1 pad: lane stride 33 -> conflict-free
};
__global__ __launch_bounds__(256) void k_pv(const unsigned char* __restrict__ pkG,
                                            const float* __restrict__ src,
                                            const float* __restrict__ dstA,
                                            const float* __restrict__ mrow,
                                            const float* __restrict__ lrow,
                                            const short* __restrict__ ht,
                                            const float* __restrict__ feat_in,
                                            const float* __restrict__ bias,
                                            const float* __restrict__ Hb,
                                            float* outg){
    __shared__ LdsU U;
    int itile = blockIdx.x, hd = blockIdx.y, b = blockIdx.z;
    int tid = threadIdx.x, wave = tid >> 6, lane = tid & 63, q = lane >> 4, nL = lane & 15;
    int rg = wave >> 1, kh = wave & 1;
    int r0 = itile * 32;
    int bh = b*H_ + hd;
    // ---- stage dst (2048 f32) and packed adj (32 rows x 64 u32) ----
    {
        const float4v* g4 = (const float4v*)(dstA + bh*N_);
        float4v* d4 = (float4v*)U.s.dst;
        d4[tid] = g4[tid];
        d4[tid + 256] = g4[tid + 256];
        const unsigned* pg = (const unsigned*)(pkG + ((size_t)(b*N_ + r0)) * (N_/8));
        #pragma unroll
        for (int k = 0; k < 8; k++){
            int idx = tid + k*256;              // [0,2048)
            U.s.pkw[(idx >> 6)*65 + (idx & 63)] = pg[idx];
        }
    }
    __syncthreads();
    int rowL = rg*16 + nL;
    int row  = r0 + rowL;
    float srcv = src[bh*N_ + row];
    float mr   = mrow[bh*N_ + row];
    const short* hp = ht + bh*Do_*N_;
    f32x4 acc[8] = {};
    int jEnd = kh*1024 + 1024;
    for (int j0 = kh*1024; j0 < jEnd; j0 += 32){
        unsigned word = U.s.pkw[rowL*65 + (j0 >> 5)];
        unsigned by = (word >> (q*8)) & 0xFF;
        int kb = j0 + q*8;
        float4v d0 = *(const float4v*)&U.s.dst[kb];
        float4v d1 = *(const float4v*)&U.s.dst[kb + 4];
        bf16x8 pf;
        #pragma unroll
        for (int t = 0; t < 8; t++){
            float dv = t < 4 ? d0[t] : d1[t-4];
            float v = srcv + dv;
            float s = v >= 0.f ? v : 0.2f*v;
            float p = __expf(s - mr);
            p = ((by >> t) & 1u) ? p : 0.0f;
            pf[t] = f2b(p);
        }
        #pragma unroll
        for (int ct = 0; ct < 8; ct++){
            bf16x8 bF = *(const bf16x8*)&hp[(ct*16 + nL)*N_ + kb];
            acc[ct] = __builtin_amdgcn_mfma_f32_16x16x32_bf16(pf, bF, acc[ct], 0, 0, 0);
        }
    }
    __syncthreads();          // staging region dead; safe to overwrite with red
    if (kh == 1){
        #pragma unroll
        for (int ct = 0; ct < 8; ct++)
            #pragma unroll
            for (int r = 0; r < 4; r++)
                U.red[rg][lane][ct*4 + r] = acc[ct][r];
    }
    __syncthreads();
    if (kh == 0){
        #pragma unroll
        for (int ct = 0; ct < 8; ct++)
            #pragma unroll
            for (int r = 0; r < 4; r++)
                acc[ct][r] += U.red[rg][lane][ct*4 + r];
        #pragma unroll
        for (int r = 0; r < 4; r++){
            int i = r0 + rg*16 + q*4 + r;       // C row = q*4+r
            float invl = 1.0f / lrow[bh*N_ + i];
            size_t base = (size_t)(b*N_ + i)*D_ + hd*Do_;
            #pragma unroll
            for (int ct = 0; ct < 8; ct++){
                int o = ct*16 + nL;             // C col = lane&15
                float v = acc[ct][r]*invl + bias[o];
                float e = v > 0.f ? v : __expf(v) - 1.0f;
                float gl = outg[base + o] + Hb[hd*Do_ + o];
                float g = 1.0f / (1.0f + __expf(-gl));
                float fi = feat_in[base + o];
                outg[base + o] = g*e + (1.0f - g)*fi;
            }
        }
    }
}

extern "C" void kernel_launch(void* const* d_in, const int* in_sizes, int n_in,
                              void* d_out, int out_size, void* d_ws, size_t ws_size,
                              hipStream_t stream){
    const float* feat = (const float*)d_in[0];
    const int*   adj  = (const int*)  d_in[1];
    const float* W    = (const float*)d_in[2];
    const float* bias = (const float*)d_in[3];
    const float* wsrc = (const float*)d_in[4];
    const float* wdst = (const float*)d_in[5];
    const float* Hw   = (const float*)d_in[6];
    const float* Hb   = (const float*)d_in[7];
    float* out = (float*)d_out;                 // f32 output per reference dtype
    char* ws = (char*)d_ws;
    // Workspace (17,825,792 bytes total):
    //   bmat [0, 2,359,296)
    //   ht   [2,359,296, 14,942,208)
    //   src  [14,942,208, 15,138,816)
    //   dst  [15,138,816, 15,335,424)
    //   mrow [15,335,424, 15,532,032)
    //   lrow [15,532,032, 15,728,640)
    //   pk   [15,728,640, 17,825,792)   packed adj bits
    short* bmat = (short*)(ws);
    short* ht   = (short*)(ws + 2359296);
    float* src  = (float*)(ws + 14942208);
    float* dst  = (float*)(ws + 15138816);
    float* mrow = (float*)(ws + 15335424);
    float* lrow = (float*)(ws + 15532032);
    unsigned char* pk = (unsigned char*)(ws + 15728640);

    hipLaunchKernelGGL(k_prep,     dim3(C2_),     dim3(256), 0, stream, W, Hw, bmat);
    hipLaunchKernelGGL(k_pack,     dim3(8192),    dim3(256), 0, stream, adj, pk);
    hipLaunchKernelGGL(k_gemm,     dim3(24, 128), dim3(256), 0, stream, feat, bmat, ht, out);
    hipLaunchKernelGGL(k_stats,    dim3(192),     dim3(256), 0, stream, ht, wsrc, wdst, src, dst);
    hipLaunchKernelGGL(k_rowstats, dim3(2048, 4), dim3(256), 0, stream, adj, src, dst, mrow, lrow);
    hipLaunchKernelGGL(k_pv,       dim3(64, 6, 4),dim3(256), 0, stream, pk, src, dst, mrow, lrow,
                       ht, feat, bias, Hb, out);
}

// Round 8
// 335.206 us; speedup vs baseline: 1.5013x; 1.3962x over previous
//
#include <hip/hip_runtime.h>
#include <hip/hip_bf16.h>

#define B_ 4
#define N_ 2048
#define D_ 768
#define H_ 6
#define Do_ 128
#define M_ (B_*N_)      // 8192
#define C2_ (2*D_)      // 1536

typedef __attribute__((ext_vector_type(8))) short bf16x8;
typedef __attribute__((ext_vector_type(4))) float f32x4;
typedef __attribute__((ext_vector_type(4))) int int4v;
typedef __attribute__((ext_vector_type(4))) float float4v;
typedef __attribute__((ext_vector_type(4))) unsigned short ushort4v;

__device__ __forceinline__ float b2f(short s){
    unsigned u = ((unsigned)(unsigned short)s) << 16;
    return __builtin_bit_cast(float, u);
}
__device__ __forceinline__ short f2b(float f){
    unsigned u = __builtin_bit_cast(unsigned, f);
    unsigned r = (u + 0x7fffu + ((u >> 16) & 1u)) >> 16;
    return (short)r;
}
__device__ __forceinline__ float fast_tanh(float x){
    float a = fabsf(x);
    float e = __expf(-2.0f * a);
    float t = (1.0f - e) / (1.0f + e);
    return copysignf(t, x);
}

// -------- Kernel A: pack B^T matrix [1536][768] (f32 -> bf16) --------
__global__ __launch_bounds__(256) void k_prep(const float* __restrict__ W,
                                              const float* __restrict__ Hw,
                                              short* __restrict__ bmat){
    int c = blockIdx.x, t = threadIdx.x;
    if (c < D_){
        int hd = c >> 7, o = c & 127;
        const float* wp = W + hd*D_*Do_ + o;
        for (int k = t; k < D_; k += 256) bmat[c*D_ + k] = f2b(wp[k*Do_]);
    } else {
        int d = c - D_;
        const float* hp = Hw + d*D_;
        for (int k = t; k < D_; k += 256) bmat[c*D_ + k] = f2b(hp[k]);
    }
}

// -------- Kernel A2: bit-pack adj (int 0/1 -> 1 bit), 67MB -> 2MB --------
__global__ __launch_bounds__(256) void k_pack(const int* __restrict__ adj,
                                              unsigned char* __restrict__ pk){
    int t = blockIdx.x*256 + threadIdx.x;
    const int* ap = adj + (size_t)t*8;
    int4v a0 = *(const int4v*)ap;
    int4v a1 = *(const int4v*)(ap + 4);
    unsigned by = 0;
    #pragma unroll
    for (int i = 0; i < 4; i++){
        by |= (a0[i] ? 1u : 0u) << i;
        by |= (a1[i] ? 1u : 0u) << (i + 4);
    }
    pk[t] = (unsigned char)by;
}

// -------- Kernel B: C[8192,1536] = A[8192,768] @ BmatT^T --------
__global__ __launch_bounds__(256) void k_gemm(const float* __restrict__ A,
                                              const short* __restrict__ Bm,
                                              short* __restrict__ ht,
                                              float* outg){
    __shared__ short As[64][72];
    __shared__ short Bs[64][72];
    int tid = threadIdx.x;
    int mBase = blockIdx.y * 64, cBase = blockIdx.x * 64;
    int wave = tid >> 6, lane = tid & 63, q = lane >> 4, nL = lane & 15;
    int wRow = (wave >> 1) * 32, wCol = (wave & 1) * 32;
    f32x4 acc[2][2] = {};
    for (int kk = 0; kk < D_; kk += 64){
        __syncthreads();
        #pragma unroll
        for (int i = 0; i < 4; i++){
            int id = tid + i*256;
            int row = id >> 4, c4 = (id & 15) * 4;
            float4v av = *(const float4v*)&A[(mBase+row)*D_ + kk + c4];
            ushort4v sv;
            #pragma unroll
            for (int t = 0; t < 4; t++) sv[t] = (unsigned short)f2b(av[t]);
            *(ushort4v*)&As[row][c4] = sv;
        }
        #pragma unroll
        for (int i = 0; i < 2; i++){
            int id = tid + i*256;
            int row = id >> 3, cs = (id & 7) * 8;
            *(int4v*)&Bs[row][cs] = *(const int4v*)&Bm[(cBase+row)*D_ + kk + cs];
        }
        __syncthreads();
        #pragma unroll
        for (int k2 = 0; k2 < 64; k2 += 32){
            bf16x8 aF[2], bF[2];
            #pragma unroll
            for (int rt = 0; rt < 2; rt++) aF[rt] = *(const bf16x8*)&As[wRow + rt*16 + nL][k2 + q*8];
            #pragma unroll
            for (int ct = 0; ct < 2; ct++) bF[ct] = *(const bf16x8*)&Bs[wCol + ct*16 + nL][k2 + q*8];
            #pragma unroll
            for (int rt = 0; rt < 2; rt++)
                #pragma unroll
                for (int ct = 0; ct < 2; ct++)
                    acc[rt][ct] = __builtin_amdgcn_mfma_f32_16x16x32_bf16(aF[rt], bF[ct], acc[rt][ct], 0, 0, 0);
        }
    }
    #pragma unroll
    for (int rt = 0; rt < 2; rt++){
        #pragma unroll
        for (int ct = 0; ct < 2; ct++){
            int c  = cBase + wCol + ct*16 + nL;
            int m0 = mBase + wRow + rt*16 + q*4;
            if (c < D_){
                int hd = c >> 7, o = c & 127;
                int b = m0 >> 11, n0 = m0 & 2047;
                ushort4v v;
                #pragma unroll
                for (int r = 0; r < 4; r++) v[r] = (unsigned short)f2b(acc[rt][ct][r]);
                *(ushort4v*)&ht[((b*H_ + hd)*Do_ + o)*N_ + n0] = v;
            } else {
                int d = c - D_;
                #pragma unroll
                for (int r = 0; r < 4; r++) outg[(size_t)(m0 + r)*D_ + d] = acc[rt][ct][r];
            }
        }
    }
}

// -------- Kernel C: attn_src/dst = tanh(h) . w --------
__global__ __launch_bounds__(256) void k_stats(const short* __restrict__ ht,
                                               const float* __restrict__ wsrc,
                                               const float* __restrict__ wdst,
                                               float* __restrict__ src,
                                               float* __restrict__ dst){
    int g = blockIdx.x * 256 + threadIdx.x;
    int bh = g >> 11, n = g & 2047;
    int hd = bh % H_;
    const short* hp = ht + bh*Do_*N_ + n;
    const float* ws = wsrc + hd*Do_;
    const float* wd = wdst + hd*Do_;
    float as = 0.f, ad = 0.f;
    for (int o = 0; o < Do_; o++){
        float t = fast_tanh(b2f(hp[o*N_]));
        as += t * ws[o];
        ad += t * wd[o];
    }
    src[g] = as; dst[g] = ad;
}

// -------- Kernel E: O = softmax(S)@h fused, no-max softmax, K-split 2x --------
// Block = 256 thr = 4 waves: wave (rh, kh); rh = row-half (32 rows via 2 A-frags),
// kh = K-half (j in [kh*1024, kh*1024+1024)). M-tile = 64 rows.
// P = adj ? exp(leaky(src_i + dst_j)) : 0  (scores bounded ~|18| -> exp safe in f32).
// l_i = sum_j P accumulated in-register, reduced cross-q (shfl) and cross-kh (LDS).
// 16 MFMA per 8 ht B-loads (2 frags share each bF).
struct StageS {
    float dst[2048];            // 8 KB
    unsigned pkw[64*65];        // packed adj bits, 65-u32 row stride
};
struct RedS {
    float red[2][64][66];       // [rh][lane][f*32+ct*4+r | 64+f]; stride 66 -> 2-way max
};
union LdsU { StageS s; RedS r; };
__global__ __launch_bounds__(256) void k_pv(const unsigned char* __restrict__ pkG,
                                            const float* __restrict__ src,
                                            const float* __restrict__ dstA,
                                            const short* __restrict__ ht,
                                            const float* __restrict__ feat_in,
                                            const float* __restrict__ bias,
                                            const float* __restrict__ Hb,
                                            float* outg){
    __shared__ LdsU U;
    __shared__ float l_sm[64];
    int itile = blockIdx.x, hd = blockIdx.y, b = blockIdx.z;
    int tid = threadIdx.x, wave = tid >> 6, lane = tid & 63, q = lane >> 4, nL = lane & 15;
    int rh = wave >> 1, kh = wave & 1;
    int r0 = itile * 64;
    int bh = b*H_ + hd;
    // ---- stage dst row (2048 f32) and packed adj (64 rows x 64 u32) ----
    {
        const float4v* g4 = (const float4v*)(dstA + bh*N_);
        float4v* d4 = (float4v*)U.s.dst;
        d4[tid] = g4[tid];
        d4[tid + 256] = g4[tid + 256];
        const unsigned* pg = (const unsigned*)(pkG + (size_t)(b*N_ + r0) * (N_/8));
        #pragma unroll
        for (int k = 0; k < 16; k++){
            int idx = tid + k*256;              // [0,4096)
            U.s.pkw[(idx >> 6)*65 + (idx & 63)] = pg[idx];
        }
    }
    __syncthreads();
    int rowL0 = rh*32 + nL;                     // frag0 row (local)
    int rowL1 = rowL0 + 16;                     // frag1 row (local)
    float srcv0 = src[bh*N_ + r0 + rowL0];
    float srcv1 = src[bh*N_ + r0 + rowL1];
    const short* hp = ht + bh*Do_*N_;
    f32x4 acc[2][8] = {};
    float lsum0 = 0.f, lsum1 = 0.f;
    int jEnd = kh*1024 + 1024;
    for (int j0 = kh*1024; j0 < jEnd; j0 += 32){
        unsigned by0 = (U.s.pkw[rowL0*65 + (j0 >> 5)] >> (q*8)) & 0xFF;
        unsigned by1 = (U.s.pkw[rowL1*65 + (j0 >> 5)] >> (q*8)) & 0xFF;
        int kb = j0 + q*8;
        float4v d0 = *(const float4v*)&U.s.dst[kb];
        float4v d1 = *(const float4v*)&U.s.dst[kb + 4];
        bf16x8 pf0, pf1;
        #pragma unroll
        for (int t = 0; t < 8; t++){
            float dv = t < 4 ? d0[t] : d1[t-4];
            float v0 = srcv0 + dv, v1 = srcv1 + dv;
            float s0 = v0 >= 0.f ? v0 : 0.2f*v0;
            float s1 = v1 >= 0.f ? v1 : 0.2f*v1;
            float p0 = ((by0 >> t) & 1u) ? __expf(s0) : 0.0f;
            float p1 = ((by1 >> t) & 1u) ? __expf(s1) : 0.0f;
            lsum0 += p0; lsum1 += p1;
            pf0[t] = f2b(p0); pf1[t] = f2b(p1);
        }
        #pragma unroll
        for (int ct = 0; ct < 8; ct++){
            bf16x8 bF = *(const bf16x8*)&hp[(ct*16 + nL)*N_ + kb];
            acc[0][ct] = __builtin_amdgcn_mfma_f32_16x16x32_bf16(pf0, bF, acc[0][ct], 0, 0, 0);
            acc[1][ct] = __builtin_amdgcn_mfma_f32_16x16x32_bf16(pf1, bF, acc[1][ct], 0, 0, 0);
        }
    }
    __syncthreads();          // staging dead; red region reuses the LDS
    if (kh == 1){
        #pragma unroll
        for (int f = 0; f < 2; f++)
            #pragma unroll
            for (int ct = 0; ct < 8; ct++)
                #pragma unroll
                for (int r = 0; r < 4; r++)
                    U.r.red[rh][lane][f*32 + ct*4 + r] = acc[f][ct][r];
        U.r.red[rh][lane][64] = lsum0;
        U.r.red[rh][lane][65] = lsum1;
    }
    __syncthreads();
    if (kh == 0){
        #pragma unroll
        for (int f = 0; f < 2; f++)
            #pragma unroll
            for (int ct = 0; ct < 8; ct++)
                #pragma unroll
                for (int r = 0; r < 4; r++)
                    acc[f][ct][r] += U.r.red[rh][lane][f*32 + ct*4 + r];
        lsum0 += U.r.red[rh][lane][64];
        lsum1 += U.r.red[rh][lane][65];
        // cross-q row-sum: lanes {nL, nL+16, nL+32, nL+48} hold partials of one row
        lsum0 += __shfl_xor(lsum0, 16); lsum0 += __shfl_xor(lsum0, 32);
        lsum1 += __shfl_xor(lsum1, 16); lsum1 += __shfl_xor(lsum1, 32);
        if (q == 0){ l_sm[rowL0] = lsum0; l_sm[rowL1] = lsum1; }
    }
    __syncthreads();
    if (kh == 0){
        #pragma unroll
        for (int f = 0; f < 2; f++){
            #pragma unroll
            for (int r = 0; r < 4; r++){
                int iL = rh*32 + f*16 + q*4 + r;      // C row = q*4+r within frag
                int i  = r0 + iL;
                float invl = 1.0f / l_sm[iL];
                size_t base = (size_t)(b*N_ + i)*D_ + hd*Do_;
                #pragma unroll
                for (int ct = 0; ct < 8; ct++){
                    int o = ct*16 + nL;               // C col = lane&15
                    float v = acc[f][ct][r]*invl + bias[o];
                    float e = v > 0.f ? v : __expf(v) - 1.0f;
                    float gl = outg[base + o] + Hb[hd*Do_ + o];
                    float g = 1.0f / (1.0f + __expf(-gl));
                    float fi = feat_in[base + o];
                    outg[base + o] = g*e + (1.0f - g)*fi;
                }
            }
        }
    }
}

extern "C" void kernel_launch(void* const* d_in, const int* in_sizes, int n_in,
                              void* d_out, int out_size, void* d_ws, size_t ws_size,
                              hipStream_t stream){
    const float* feat = (const float*)d_in[0];
    const int*   adj  = (const int*)  d_in[1];
    const float* W    = (const float*)d_in[2];
    const float* bias = (const float*)d_in[3];
    const float* wsrc = (const float*)d_in[4];
    const float* wdst = (const float*)d_in[5];
    const float* Hw   = (const float*)d_in[6];
    const float* Hb   = (const float*)d_in[7];
    float* out = (float*)d_out;
    char* ws = (char*)d_ws;
    // Workspace (17,432,576 bytes):
    //   bmat [0, 2,359,296)
    //   ht   [2,359,296, 14,942,208)
    //   src  [14,942,208, 15,138,816)
    //   dst  [15,138,816, 15,335,424)
    //   pk   [15,335,424, 17,432,576)
    short* bmat = (short*)(ws);
    short* ht   = (short*)(ws + 2359296);
    float* src  = (float*)(ws + 14942208);
    float* dst  = (float*)(ws + 15138816);
    unsigned char* pk = (unsigned char*)(ws + 15335424);

    hipLaunchKernelGGL(k_prep,  dim3(C2_),      dim3(256), 0, stream, W, Hw, bmat);
    hipLaunchKernelGGL(k_pack,  dim3(8192),     dim3(256), 0, stream, adj, pk);
    hipLaunchKernelGGL(k_gemm,  dim3(24, 128),  dim3(256), 0, stream, feat, bmat, ht, out);
    hipLaunchKernelGGL(k_stats, dim3(192),      dim3(256), 0, stream, ht, wsrc, wdst, src, dst);
    hipLaunchKernelGGL(k_pv,    dim3(32, 6, 4), dim3(256), 0, stream, pk, src, dst,
                       ht, feat, bias, Hb, out);
}

// Round 9
// 318.857 us; speedup vs baseline: 1.5783x; 1.0513x over previous
//
#include <hip/hip_runtime.h>
#include <hip/hip_bf16.h>

#define B_ 4
#define N_ 2048
#define D_ 768
#define H_ 6
#define Do_ 128
#define M_ (B_*N_)      // 8192
#define C2_ (2*D_)      // 1536
#define SROW 49152      // B_*H_*N_

typedef __attribute__((ext_vector_type(8))) short bf16x8;
typedef __attribute__((ext_vector_type(4))) float f32x4;
typedef __attribute__((ext_vector_type(4))) int int4v;
typedef __attribute__((ext_vector_type(2))) int int2v;
typedef __attribute__((ext_vector_type(4))) float float4v;
typedef __attribute__((ext_vector_type(4))) unsigned short ushort4v;

__device__ __forceinline__ float b2f(short s){
    unsigned u = ((unsigned)(unsigned short)s) << 16;
    return __builtin_bit_cast(float, u);
}
__device__ __forceinline__ short f2b(float f){
    unsigned u = __builtin_bit_cast(unsigned, f);
    unsigned r = (u + 0x7fffu + ((u >> 16) & 1u)) >> 16;
    return (short)r;
}
// pack two f32 -> two bf16 (round-half-up) in one v_perm
__device__ __forceinline__ int pk2(float a, float b){
    unsigned ua = __builtin_bit_cast(unsigned, a) + 0x8000u;
    unsigned ub = __builtin_bit_cast(unsigned, b) + 0x8000u;
    return (int)__builtin_amdgcn_perm(ub, ua, 0x07060302u); // lo16=hi(ua), hi16=hi(ub)
}
__device__ __forceinline__ float fast_tanh(float x){
    float a = fabsf(x);
    float e = __expf(-2.0f * a);
    float t = (1.0f - e) / (1.0f + e);
    return copysignf(t, x);
}

// -------- Kernel A: pack B^T matrix (f32->bf16) + bit-pack adj, one launch --------
__global__ __launch_bounds__(256) void k_prep_pack(const float* __restrict__ W,
                                                   const float* __restrict__ Hw,
                                                   const int* __restrict__ adj,
                                                   short* __restrict__ bmat,
                                                   unsigned char* __restrict__ pk){
    int bid = blockIdx.x, t = threadIdx.x;
    if (bid < C2_){
        int c = bid;
        if (c < D_){
            int hd = c >> 7, o = c & 127;
            const float* wp = W + hd*D_*Do_ + o;
            for (int k = t; k < D_; k += 256) bmat[c*D_ + k] = f2b(wp[k*Do_]);
        } else {
            int d = c - D_;
            const float* hp = Hw + d*D_;
            for (int k = t; k < D_; k += 256) bmat[c*D_ + k] = f2b(hp[k]);
        }
    } else {
        int g = (bid - C2_)*256 + t;            // one byte per thread
        const int* ap = adj + (size_t)g*8;
        int4v a0 = *(const int4v*)ap;
        int4v a1 = *(const int4v*)(ap + 4);
        unsigned by = 0;
        #pragma unroll
        for (int i = 0; i < 4; i++){
            by |= (a0[i] ? 1u : 0u) << i;
            by |= (a1[i] ? 1u : 0u) << (i + 4);
        }
        pk[g] = (unsigned char)by;
    }
}

// -------- Kernel B: C[8192,1536] = A[8192,768] @ Bm^T, 128x128 tile --------
// 4 waves, each computes a 64x64 quadrant (4x4 16x16x32 frags).
// h (c<768) stored transposed ht[(bh*128+o)*2048+n] bf16; gate (c>=768) f32 -> d_out.
__global__ __launch_bounds__(256) void k_gemm(const float* __restrict__ A,
                                              const short* __restrict__ Bm,
                                              short* __restrict__ ht,
                                              float* outg){
    __shared__ short As[128][72];   // row stride 144B (16B-mult), 36.9KB total
    __shared__ short Bs[128][72];
    int tid = threadIdx.x;
    int mBase = blockIdx.y * 128, cBase = blockIdx.x * 128;
    int wave = tid >> 6, lane = tid & 63, q = lane >> 4, nL = lane & 15;
    int wr = (wave >> 1) * 64, wc = (wave & 1) * 64;
    f32x4 acc[4][4] = {};
    for (int kk = 0; kk < D_; kk += 64){
        __syncthreads();
        #pragma unroll
        for (int i = 0; i < 8; i++){            // A: 128 rows x 64 k, f32 -> bf16
            int idx = tid + i*256;              // [0,2048)
            int row = idx >> 4, c4 = (idx & 15) * 4;
            float4v av = *(const float4v*)&A[(mBase+row)*D_ + kk + c4];
            int2v w; w[0] = pk2(av[0], av[1]); w[1] = pk2(av[2], av[3]);
            *(int2v*)&As[row][c4] = w;
        }
        #pragma unroll
        for (int i = 0; i < 4; i++){            // B: 128 rows x 64 k, bf16
            int idx = tid + i*256;              // [0,1024)
            int row = idx >> 3, cs = (idx & 7) * 8;
            *(int4v*)&Bs[row][cs] = *(const int4v*)&Bm[(cBase+row)*D_ + kk + cs];
        }
        __syncthreads();
        #pragma unroll
        for (int k2 = 0; k2 < 64; k2 += 32){
            bf16x8 aF[4], bF[4];
            #pragma unroll
            for (int rt = 0; rt < 4; rt++) aF[rt] = *(const bf16x8*)&As[wr + rt*16 + nL][k2 + q*8];
            #pragma unroll
            for (int ct = 0; ct < 4; ct++) bF[ct] = *(const bf16x8*)&Bs[wc + ct*16 + nL][k2 + q*8];
            #pragma unroll
            for (int rt = 0; rt < 4; rt++)
                #pragma unroll
                for (int ct = 0; ct < 4; ct++)
                    acc[rt][ct] = __builtin_amdgcn_mfma_f32_16x16x32_bf16(aF[rt], bF[ct], acc[rt][ct], 0, 0, 0);
        }
    }
    if (cBase < D_){
        int hd = cBase >> 7;                    // 128-wide tile = exactly one head
        #pragma unroll
        for (int rt = 0; rt < 4; rt++){
            #pragma unroll
            for (int ct = 0; ct < 4; ct++){
                int o  = (wc + ct*16 + nL) & 127;
                int m0 = mBase + wr + rt*16 + q*4;
                int b = m0 >> 11, n0 = m0 & 2047;
                ushort4v v;
                #pragma unroll
                for (int r = 0; r < 4; r++) v[r] = (unsigned short)f2b(acc[rt][ct][r]);
                *(ushort4v*)&ht[((b*H_ + hd)*Do_ + o)*N_ + n0] = v;
            }
        }
    } else {
        #pragma unroll
        for (int rt = 0; rt < 4; rt++){
            #pragma unroll
            for (int ct = 0; ct < 4; ct++){
                int d  = cBase - D_ + wc + ct*16 + nL;
                int m0 = mBase + wr + rt*16 + q*4;
                #pragma unroll
                for (int r = 0; r < 4; r++) outg[(size_t)(m0 + r)*D_ + d] = acc[rt][ct][r];
            }
        }
    }
}

// -------- Kernel C: attn_src/dst partials = tanh(h).w over o-range, 4-way split --------
__global__ __launch_bounds__(256) void k_stats(const short* __restrict__ ht,
                                               const float* __restrict__ wsrc,
                                               const float* __restrict__ wdst,
                                               float* __restrict__ srcP,
                                               float* __restrict__ dstP){
    int g = blockIdx.x * 256 + threadIdx.x;     // g = bh*2048 + n
    int y = blockIdx.y, o0 = y * 32;
    int bh = g >> 11, n = g & 2047;
    int hd = bh % H_;
    const short* hp = ht + bh*Do_*N_ + n + o0*N_;
    const float* ws = wsrc + hd*Do_ + o0;
    const float* wd = wdst + hd*Do_ + o0;
    float as = 0.f, ad = 0.f;
    for (int o = 0; o < 32; o++){
        float t = fast_tanh(b2f(hp[o*N_]));
        as += t * ws[o];
        ad += t * wd[o];
    }
    srcP[y*SROW + g] = as; dstP[y*SROW + g] = ad;
}

// -------- Kernel E: O = softmax(S)@h fused --------
// P = adj ? exp(leaky(src_i+dst_j)) : 0 = adj ? max(e1_i*E1_j, e2_i*E2_j) : 0.
// E1/E2 staged in LDS (no exp in hot loop). l = P@ones via extra MFMA (C-row
// layout q*4+r matches epilogue indexing). 2-phase cross-kh reduction; wave kh
// epilogues frag kh (16 rows each).
struct StageS {
    float E1[2048];             // 8KB
    float E2[2048];             // 8KB
    unsigned pkw[64*65];        // 16.6KB, 65-u32 row stride
};
struct RedS { float red[2][64][37]; };  // 18.9KB; stride 37 words -> 2-way max
union LdsU { StageS s; RedS r; };
__global__ __launch_bounds__(256) void k_pv(const unsigned char* __restrict__ pkG,
                                            const float* __restrict__ srcP,
                                            const float* __restrict__ dstP,
                                            const short* __restrict__ ht,
                                            const float* __restrict__ feat_in,
                                            const float* __restrict__ bias,
                                            const float* __restrict__ Hb,
                                            float* outg){
    __shared__ LdsU U;
    int itile = blockIdx.x, hd = blockIdx.y, b = blockIdx.z;
    int tid = threadIdx.x, wave = tid >> 6, lane = tid & 63, q = lane >> 4, nL = lane & 15;
    int rh = wave >> 1, kh = wave & 1;
    int r0 = itile * 64;
    int bh = b*H_ + hd;
    // ---- stage E1/E2 (from 4-way dst partials) and packed adj (64 rows) ----
    {
        const float4v* g0 = (const float4v*)(dstP + bh*N_);
        const float4v* g1 = (const float4v*)(dstP + SROW + bh*N_);
        const float4v* g2 = (const float4v*)(dstP + 2*SROW + bh*N_);
        const float4v* g3 = (const float4v*)(dstP + 3*SROW + bh*N_);
        #pragma unroll
        for (int h = 0; h < 2; h++){
            int c4 = tid*2 + h;
            float4v d = g0[c4] + g1[c4] + g2[c4] + g3[c4];
            #pragma unroll
            for (int t = 0; t < 4; t++){
                U.s.E1[c4*4 + t] = __expf(d[t]);
                U.s.E2[c4*4 + t] = __expf(0.2f * d[t]);
            }
        }
        const unsigned* pg = (const unsigned*)(pkG + (size_t)(b*N_ + r0) * (N_/8));
        #pragma unroll
        for (int k = 0; k < 16; k++){
            int idx = tid + k*256;              // [0,4096)
            U.s.pkw[(idx >> 6)*65 + (idx & 63)] = pg[idx];
        }
    }
    __syncthreads();
    int rowL0 = rh*32 + nL, rowL1 = rowL0 + 16;
    int gi0 = bh*N_ + r0 + rowL0, gi1 = bh*N_ + r0 + rowL1;
    float s0 = srcP[gi0] + srcP[SROW+gi0] + srcP[2*SROW+gi0] + srcP[3*SROW+gi0];
    float s1 = srcP[gi1] + srcP[SROW+gi1] + srcP[2*SROW+gi1] + srcP[3*SROW+gi1];
    float e1r0 = __expf(s0), e2r0 = __expf(0.2f*s0);
    float e1r1 = __expf(s1), e2r1 = __expf(0.2f*s1);
    bf16x8 vone;
    #pragma unroll
    for (int t = 0; t < 8; t++) vone[t] = (short)0x3F80;   // bf16 1.0
    const short* hp = ht + bh*Do_*N_;
    f32x4 acc[2][8] = {};
    f32x4 accl0 = {}, accl1 = {};
    int base0 = rowL0*65, base1 = rowL1*65;
    int jEnd = kh*1024 + 1024;
    for (int j0 = kh*1024; j0 < jEnd; j0 += 32){
        unsigned by0 = (U.s.pkw[base0 + (j0 >> 5)] >> (q*8)) & 0xFF;
        unsigned by1 = (U.s.pkw[base1 + (j0 >> 5)] >> (q*8)) & 0xFF;
        int kb = j0 + q*8;
        float4v E1a = *(const float4v*)&U.s.E1[kb];
        float4v E1b = *(const float4v*)&U.s.E1[kb + 4];
        float4v E2a = *(const float4v*)&U.s.E2[kb];
        float4v E2b = *(const float4v*)&U.s.E2[kb + 4];
        float p0[8], p1[8];
        #pragma unroll
        for (int t = 0; t < 8; t++){
            float E1t = t < 4 ? E1a[t] : E1b[t-4];
            float E2t = t < 4 ? E2a[t] : E2b[t-4];
            float a0 = fmaxf(e1r0*E1t, e2r0*E2t);
            float a1 = fmaxf(e1r1*E1t, e2r1*E2t);
            p0[t] = ((by0 >> t) & 1u) ? a0 : 0.0f;
            p1[t] = ((by1 >> t) & 1u) ? a1 : 0.0f;
        }
        int4v pi0, pi1;
        #pragma unroll
        for (int tp = 0; tp < 4; tp++){
            pi0[tp] = pk2(p0[2*tp], p0[2*tp+1]);
            pi1[tp] = pk2(p1[2*tp], p1[2*tp+1]);
        }
        bf16x8 pf0 = __builtin_bit_cast(bf16x8, pi0);
        bf16x8 pf1 = __builtin_bit_cast(bf16x8, pi1);
        #pragma unroll
        for (int ct = 0; ct < 8; ct++){
            bf16x8 bF = *(const bf16x8*)&hp[(ct*16 + nL)*N_ + kb];
            acc[0][ct] = __builtin_amdgcn_mfma_f32_16x16x32_bf16(pf0, bF, acc[0][ct], 0, 0, 0);
            acc[1][ct] = __builtin_amdgcn_mfma_f32_16x16x32_bf16(pf1, bF, acc[1][ct], 0, 0, 0);
        }
        accl0 = __builtin_amdgcn_mfma_f32_16x16x32_bf16(pf0, vone, accl0, 0, 0, 0);
        accl1 = __builtin_amdgcn_mfma_f32_16x16x32_bf16(pf1, vone, accl1, 0, 0, 0);
    }
    // ---- 2-phase cross-kh reduction (staging LDS reused) ----
    __syncthreads();
    if (kh == 1){
        #pragma unroll
        for (int ct = 0; ct < 8; ct++)
            #pragma unroll
            for (int r = 0; r < 4; r++) U.r.red[rh][lane][ct*4 + r] = acc[0][ct][r];
        #pragma unroll
        for (int r = 0; r < 4; r++) U.r.red[rh][lane][32 + r] = accl0[r];
    }
    __syncthreads();
    if (kh == 0){
        #pragma unroll
        for (int ct = 0; ct < 8; ct++)
            #pragma unroll
            for (int r = 0; r < 4; r++) acc[0][ct][r] += U.r.red[rh][lane][ct*4 + r];
        #pragma unroll
        for (int r = 0; r < 4; r++) accl0[r] += U.r.red[rh][lane][32 + r];
    }
    __syncthreads();
    if (kh == 0){
        #pragma unroll
        for (int ct = 0; ct < 8; ct++)
            #pragma unroll
            for (int r = 0; r < 4; r++) U.r.red[rh][lane][ct*4 + r] = acc[1][ct][r];
        #pragma unroll
        for (int r = 0; r < 4; r++) U.r.red[rh][lane][32 + r] = accl1[r];
    }
    __syncthreads();
    if (kh == 1){
        #pragma unroll
        for (int ct = 0; ct < 8; ct++)
            #pragma unroll
            for (int r = 0; r < 4; r++) acc[1][ct][r] += U.r.red[rh][lane][ct*4 + r];
        #pragma unroll
        for (int r = 0; r < 4; r++) accl1[r] += U.r.red[rh][lane][32 + r];
    }
    // ---- epilogue: wave kh handles frag kh (16 rows) ----
    {
        int f = kh;
        f32x4 accl = f ? accl1 : accl0;
        #pragma unroll
        for (int r = 0; r < 4; r++){
            int i = r0 + rh*32 + f*16 + q*4 + r;
            float invl = 1.0f / accl[r];
            size_t base = (size_t)(b*N_ + i)*D_ + hd*Do_;
            #pragma unroll
            for (int ct = 0; ct < 8; ct++){
                int o = ct*16 + nL;
                float v = acc[f][ct][r]*invl + bias[o];
                float e = v > 0.f ? v : __expf(v) - 1.0f;
                float gl = outg[base + o] + Hb[hd*Do_ + o];
                float g = 1.0f / (1.0f + __expf(-gl));
                float fi = feat_in[base + o];
                outg[base + o] = g*e + (1.0f - g)*fi;
            }
        }
    }
}

extern "C" void kernel_launch(void* const* d_in, const int* in_sizes, int n_in,
                              void* d_out, int out_size, void* d_ws, size_t ws_size,
                              hipStream_t stream){
    const float* feat = (const float*)d_in[0];
    const int*   adj  = (const int*)  d_in[1];
    const float* W    = (const float*)d_in[2];
    const float* bias = (const float*)d_in[3];
    const float* wsrc = (const float*)d_in[4];
    const float* wdst = (const float*)d_in[5];
    const float* Hw   = (const float*)d_in[6];
    const float* Hb   = (const float*)d_in[7];
    float* out = (float*)d_out;
    char* ws = (char*)d_ws;
    // Workspace (18,612,224 bytes):
    //   bmat [0, 2,359,296)
    //   ht   [2,359,296, 14,942,208)
    //   srcP [14,942,208, 15,728,640)   4 x 49152 f32 partials
    //   dstP [15,728,640, 16,515,072)
    //   pk   [16,515,072, 18,612,224)
    short* bmat = (short*)(ws);
    short* ht   = (short*)(ws + 2359296);
    float* srcP = (float*)(ws + 14942208);
    float* dstP = (float*)(ws + 15728640);
    unsigned char* pk = (unsigned char*)(ws + 16515072);

    hipLaunchKernelGGL(k_prep_pack, dim3(C2_ + 8192), dim3(256), 0, stream, W, Hw, adj, bmat, pk);
    hipLaunchKernelGGL(k_gemm,      dim3(12, 64),     dim3(256), 0, stream, feat, bmat, ht, out);
    hipLaunchKernelGGL(k_stats,     dim3(192, 4),     dim3(256), 0, stream, ht, wsrc, wdst, srcP, dstP);
    hipLaunchKernelGGL(k_pv,        dim3(32, 6, 4),   dim3(256), 0, stream, pk, srcP, dstP,
                       ht, feat, bias, Hb, out);
}